// Round 9
// baseline (413.103 us; speedup 1.0000x reference)
//
#include <hip/hip_runtime.h>
#include <hip/hip_bf16.h>

// FlexibleGCN forward on MI355X — Round 17 (R16 ws-layout fix: hp/h1 were
// allocated at half size -> overlap -> absmax 2.28; *16 -> *32 ints/row):
//  * Direct-atomic CSR build: zero -> hist (atomicAdd deg) -> alloc
//    (wave-scan bump allocator) -> scatter (atomicAdd cur[dst]).
//  * scatter fused into gemm1's dispatch via block-range split.
//  * agg (depth-16, 2048-block grid-stride), gemm2, fc: R14-identical.

constexpr int IN_DIM  = 128;
constexpr int HDIM    = 64;
constexpr int SB      = 256;    // scatter blocks appended to gemm1 grid

__device__ __forceinline__ float bf2f(unsigned int u) {
    return __uint_as_float(u << 16);
}
__device__ __forceinline__ unsigned short f2bf_bits(float f) {
    __hip_bfloat16 b = __float2bfloat16(f);
    return *(unsigned short*)&b;
}

// ---------- CSR build (direct atomic) ----------

__global__ void zero_kernel(int* __restrict__ deg, int* __restrict__ total,
                            unsigned int* __restrict__ hp_rowN, int N) {
    int i = blockIdx.x * 256 + threadIdx.x;
    int step = gridDim.x * 256;
    for (; i < N; i += step) deg[i] = 0;
    if (blockIdx.x == 0 && threadIdx.x == 0) *total = 0;
    if (blockIdx.x == 1 && threadIdx.x < 32) hp_rowN[threadIdx.x] = 0u;
}

__global__ void hist_kernel(const int* __restrict__ dst, int* __restrict__ deg, int E) {
    int i = blockIdx.x * 256 + threadIdx.x;
    int step = gridDim.x * 256;
    for (; i < E; i += step) atomicAdd(&deg[dst[i]], 1);
}

// Per-node padded range via wave-level bump allocation: one global atomic
// per wave (not per thread). esrc segment order is arbitrary; rows[] is
// the source of truth. Pad slots point at node N (zeroed hp row).
__global__ void alloc_kernel(const int* __restrict__ deg, int* __restrict__ total,
                             int2* __restrict__ rows, int* __restrict__ cur,
                             float* __restrict__ dinv, int* __restrict__ esrc, int N) {
    int idx = blockIdx.x * 256 + threadIdx.x;
    int lane = threadIdx.x & 63;
    int dg = (idx < N) ? deg[idx] : 0;
    int pv = (dg + 7) & ~7;
    int incl = pv;
#pragma unroll
    for (int off = 1; off < 64; off <<= 1) {
        int t = __shfl_up(incl, off, 64);
        if (lane >= off) incl += t;
    }
    int wtot = __shfl(incl, 63, 64);
    int base = 0;
    if (lane == 63) base = atomicAdd(total, wtot);
    base = __shfl(base, 63, 64);
    int start = base + incl - pv;
    if (idx < N) {
        rows[idx] = make_int2(start, start + pv);
        cur[idx] = start;
        dinv[idx] = rsqrtf((float)dg + 1.0f);     // +1 self-loop
        for (int q = dg; q < pv; ++q) esrc[start + q] = N;
    }
}

// ---------- dense layers (R14 gemm_body) ----------

template<int K, bool IBF16, bool SCALE, bool BIAS, bool OBF16>
__device__ __forceinline__ void gemm_body(
        const void* __restrict__ Xv, const float* __restrict__ W,
        const float* __restrict__ bias, const float* __restrict__ dinv,
        void* __restrict__ Yv, int n, int bid) {
    constexpr int KC = 32;
    constexpr int XSTR = 132;                 // floats
    __shared__ float Xt[KC * XSTR];           // 16.9 KB
    __shared__ float Ws[KC * 64];             // 8 KB
    const int tid = threadIdx.x;
    const int node0 = bid * 128;
    const int r0 = (tid >> 4) * 8;            // 0..120
    const int c0 = (tid & 15) * 4;            // 0..60

    float acc[8][4];
#pragma unroll
    for (int a = 0; a < 8; ++a)
#pragma unroll
        for (int b = 0; b < 4; ++b) acc[a][b] = 0.f;

    for (int kc = 0; kc < K; kc += KC) {
        __syncthreads();
#pragma unroll
        for (int i = 0; i < 4; ++i) {
            int s = tid + i * 256;
            int row = s >> 3;
            int kq = s & 7;
            int grow = node0 + row;
            float4 v = make_float4(0.f, 0.f, 0.f, 0.f);
            if (grow < n) {
                if (IBF16) {
                    uint2 u = *(const uint2*)&((const unsigned short*)Xv)[(size_t)grow * K + kc + kq * 4];
                    v.x = bf2f(u.x & 0xffff); v.y = bf2f(u.x >> 16);
                    v.z = bf2f(u.y & 0xffff); v.w = bf2f(u.y >> 16);
                } else {
                    v = *(const float4*)&((const float*)Xv)[(size_t)grow * K + kc + kq * 4];
                }
            }
            Xt[(kq * 4 + 0) * XSTR + row] = v.x;
            Xt[(kq * 4 + 1) * XSTR + row] = v.y;
            Xt[(kq * 4 + 2) * XSTR + row] = v.z;
            Xt[(kq * 4 + 3) * XSTR + row] = v.w;
        }
#pragma unroll
        for (int i = 0; i < 2; ++i) {
            int s = tid + i * 256;
            *(float4*)&Ws[s * 4] = *(const float4*)&W[(size_t)kc * 64 + s * 4];
        }
        __syncthreads();
#pragma unroll
        for (int kk = 0; kk < KC; kk += 4) {
            float4 xa[4][2];
            float4 wv[4];
#pragma unroll
            for (int i = 0; i < 4; ++i) {
                xa[i][0] = *(const float4*)&Xt[(kk + i) * XSTR + r0];
                xa[i][1] = *(const float4*)&Xt[(kk + i) * XSTR + r0 + 4];
                wv[i]    = *(const float4*)&Ws[(kk + i) * 64 + c0];
            }
#pragma unroll
            for (int i = 0; i < 4; ++i) {
                const float* xp = (const float*)&xa[i][0];
                const float* wp = (const float*)&wv[i];
#pragma unroll
                for (int rr = 0; rr < 8; ++rr)
#pragma unroll
                    for (int cc = 0; cc < 4; ++cc)
                        acc[rr][cc] += xp[rr] * wp[cc];
            }
        }
    }
#pragma unroll
    for (int rr = 0; rr < 8; ++rr) {
        int node = node0 + r0 + rr;
        if (node < n) {
            float d = SCALE ? dinv[node] : 1.0f;
            float t[4];
#pragma unroll
            for (int cc = 0; cc < 4; ++cc) {
                float v = acc[rr][cc];
                if (BIAS) v += bias[c0 + cc];
                t[cc] = v * d;
            }
            if (OBF16) {
                __hip_bfloat16 vb[4];
#pragma unroll
                for (int cc = 0; cc < 4; ++cc) vb[cc] = __float2bfloat16(t[cc]);
                *(uint2*)&((__hip_bfloat16*)Yv)[(size_t)node * 64 + c0] = *(uint2*)vb;
            } else {
                *(float4*)&((float*)Yv)[(size_t)node * 64 + c0] = *(float4*)t;
            }
        }
    }
}

// gemm1 tiles on blocks [0,gB); edge scatter on blocks [gB, gB+SB).
// Both depend only on alloc_kernel; all blocks co-resident -> overlap.
__global__ __launch_bounds__(256, 4) void gemm1_scatter_kernel(
        const float* __restrict__ X, const float* __restrict__ W,
        const float* __restrict__ dinv, unsigned short* __restrict__ Y,
        const int* __restrict__ src, const int* __restrict__ dst,
        int* __restrict__ cur, int* __restrict__ esrc, int gB, int E, int n) {
    if ((int)blockIdx.x >= gB) {
        int i = ((int)blockIdx.x - gB) * 256 + threadIdx.x;
        int step = SB * 256;
        for (; i < E; i += step) {
            int d = dst[i];
            int p = atomicAdd(&cur[d], 1);
            esrc[p] = src[i];
        }
        return;
    }
    gemm_body<IN_DIM, false, true, false, true>(X, W, nullptr, dinv, Y, n, blockIdx.x);
}

__global__ __launch_bounds__(256, 4) void gemm2_kernel(
        const void* X, const float* W, const float* dinv, void* Y, int n) {
    gemm_body<HDIM, true, true, false, true>(X, W, nullptr, dinv, Y, n, blockIdx.x);
}
__global__ __launch_bounds__(256, 4) void fc_kernel(
        const float* X, const float* W, const float* bias, void* Y, int n) {
    gemm_body<HDIM, false, false, true, false>(X, W, bias, nullptr, Y, n, blockIdx.x);
}

// ---------- aggregation: CSR-vector, 8 lanes per node (R14) ----------

template<bool OBF16>
__global__ __launch_bounds__(256) void agg_kernel(
        const uint4* __restrict__ hp4, const int* __restrict__ esrc,
        const int2* __restrict__ rows, const float* __restrict__ dinv,
        const float* __restrict__ bias, void* __restrict__ out, int n) {
    const int lane = threadIdx.x & 63;
    const int j = lane & 7;
    const int step = gridDim.x * 32;
    for (int idx = blockIdx.x * 32 + (threadIdx.x >> 6) * 8 + (lane >> 3);
         idx < n; idx += step) {
        const int node = idx;
        const int2 be = rows[node];

        float acc[8];
        {   // self-loop: own row
            uint4 u = hp4[(size_t)node * 8 + j];
            acc[0] = bf2f(u.x & 0xffff); acc[1] = bf2f(u.x >> 16);
            acc[2] = bf2f(u.y & 0xffff); acc[3] = bf2f(u.y >> 16);
            acc[4] = bf2f(u.z & 0xffff); acc[5] = bf2f(u.z >> 16);
            acc[6] = bf2f(u.w & 0xffff); acc[7] = bf2f(u.w >> 16);
        }
        int k = be.x;
        for (; k + 16 <= be.y; k += 16) {       // depth-16 batches
            int s[16];
#pragma unroll
            for (int i = 0; i < 16; ++i)
                s[i] = __builtin_nontemporal_load(&esrc[k + i]);
            uint4 u[16];
#pragma unroll
            for (int i = 0; i < 16; ++i)
                u[i] = hp4[(size_t)s[i] * 8 + j];
#pragma unroll
            for (int i = 0; i < 16; ++i) {
                acc[0] += bf2f(u[i].x & 0xffff); acc[1] += bf2f(u[i].x >> 16);
                acc[2] += bf2f(u[i].y & 0xffff); acc[3] += bf2f(u[i].y >> 16);
                acc[4] += bf2f(u[i].z & 0xffff); acc[5] += bf2f(u[i].z >> 16);
                acc[6] += bf2f(u[i].w & 0xffff); acc[7] += bf2f(u[i].w >> 16);
            }
        }
        if (k < be.y) {                          // padded => exactly 8 left
            int s[8];
#pragma unroll
            for (int i = 0; i < 8; ++i)
                s[i] = __builtin_nontemporal_load(&esrc[k + i]);
            uint4 u[8];
#pragma unroll
            for (int i = 0; i < 8; ++i)
                u[i] = hp4[(size_t)s[i] * 8 + j];
#pragma unroll
            for (int i = 0; i < 8; ++i) {
                acc[0] += bf2f(u[i].x & 0xffff); acc[1] += bf2f(u[i].x >> 16);
                acc[2] += bf2f(u[i].y & 0xffff); acc[3] += bf2f(u[i].y >> 16);
                acc[4] += bf2f(u[i].z & 0xffff); acc[5] += bf2f(u[i].z >> 16);
                acc[6] += bf2f(u[i].w & 0xffff); acc[7] += bf2f(u[i].w >> 16);
            }
        }
        const float d = dinv[node];
        float o[8];
#pragma unroll
        for (int t = 0; t < 8; ++t)
            o[t] = fmaxf(fmaf(d, acc[t], bias[8 * j + t]), 0.f);

        if (OBF16) {
            uint4 pk;
            pk.x = (unsigned)f2bf_bits(o[0]) | ((unsigned)f2bf_bits(o[1]) << 16);
            pk.y = (unsigned)f2bf_bits(o[2]) | ((unsigned)f2bf_bits(o[3]) << 16);
            pk.z = (unsigned)f2bf_bits(o[4]) | ((unsigned)f2bf_bits(o[5]) << 16);
            pk.w = (unsigned)f2bf_bits(o[6]) | ((unsigned)f2bf_bits(o[7]) << 16);
            ((uint4*)out)[(size_t)node * 8 + j] = pk;
        } else {
            ((float4*)out)[(size_t)node * 16 + 2 * j]     = make_float4(o[0], o[1], o[2], o[3]);
            ((float4*)out)[(size_t)node * 16 + 2 * j + 1] = make_float4(o[4], o[5], o[6], o[7]);
        }
    }
}

extern "C" void kernel_launch(void* const* d_in, const int* in_sizes, int n_in,
                              void* d_out, int out_size, void* d_ws, size_t ws_size,
                              hipStream_t stream) {
    const float* x   = (const float*)d_in[0];
    const float* W1  = (const float*)d_in[1];
    const float* b1  = (const float*)d_in[2];
    const float* W2  = (const float*)d_in[3];
    const float* b2  = (const float*)d_in[4];
    const float* Wfc = (const float*)d_in[5];
    const float* bfc = (const float*)d_in[6];
    const int*  eidx = (const int*)d_in[7];

    const int N = in_sizes[0] / IN_DIM;     // 100000
    const int E = in_sizes[7] / 2;          // 1600000
    const int* src = eidx;
    const int* dst = eidx + E;

    const int EP = E + 7 * ((N + 7) & ~7) + 16;   // padded esrc capacity

    // ws layout (ints, regions 16B-aligned):
    // rows[N] int2 | dinv[N] | deg[N] | cur[N] | total[4]
    //   | esrc[EP] | hp[(N+1) rows x 128B] (row N = zero) | h1[N rows x 128B]
    int* p = (int*)d_ws;
    int2* rows = (int2*)p;           p += (size_t)2 * N + 2;
    float* dinv = (float*)p;         p += (size_t)((N + 3) & ~3);
    int* deg = p;                    p += (size_t)((N + 3) & ~3);
    int* cur = p;                    p += (size_t)((N + 3) & ~3);
    int* total = p;                  p += 4;
    int* esrc = p;                   p += (size_t)((EP + 3) & ~3);
    unsigned short* hp = (unsigned short*)p;   p += (size_t)(N + 1) * 32;  // 32 ints = 128B/row
    unsigned short* h1 = (unsigned short*)p;   p += (size_t)N * 32;
    unsigned int* hp_rowN = (unsigned int*)(hp + (size_t)N * 64);

    float* emb    = (float*)d_out;
    float* logits = emb + (size_t)N * HDIM;

    const int gB = (N + 127) / 128;         // 782 gemm tiles
    const int aBlocks = 2048;               // 256 CU x 8 blocks, grid-stride

    // ---- CSR build (direct atomic) ----
    zero_kernel<<<256, 256, 0, stream>>>(deg, total, hp_rowN, N);
    hist_kernel<<<512, 256, 0, stream>>>(dst, deg, E);
    alloc_kernel<<<(N + 255) / 256, 256, 0, stream>>>(deg, total, rows, cur, dinv, esrc, N);

    // ---- layer 1 gemm  ||  edge scatter (independent, one dispatch) ----
    gemm1_scatter_kernel<<<gB + SB, 256, 0, stream>>>(
        x, W1, dinv, hp, src, dst, cur, esrc, gB, E, N);

    // ---- layer 1 agg ----
    agg_kernel<true><<<aBlocks, 256, 0, stream>>>(
        (const uint4*)hp, esrc, rows, dinv, b1, h1, N);

    // ---- layer 2 ----
    gemm2_kernel<<<gB, 256, 0, stream>>>(h1, W2, dinv, hp, N);
    agg_kernel<false><<<aBlocks, 256, 0, stream>>>(
        (const uint4*)hp, esrc, rows, dinv, b2, emb, N);

    // ---- FC head ----
    fc_kernel<<<gB, 256, 0, stream>>>(emb, Wfc, bfc, logits, N);
}

// Round 10
// 350.144 us; speedup vs baseline: 1.1798x; 1.1798x over previous
//
#include <hip/hip_runtime.h>
#include <hip/hip_bf16.h>

// FlexibleGCN forward on MI355X — Round 18:
//  * Revert R17 atomic scatter (4B random writes -> 114MB write amplification).
//    Back to R14's bucket-staged CSR (sequential bucket-cursor writes).
//  * gemm1 writes UNSCALED bf16 hp -> it no longer depends on the CSR chain:
//    half-A fused with binA_count, half-B fused with binA_scatter (block-range
//    splits). finalize rescales hp rows by dinv in-place (+1 bf16 round, ok).
//  * scanblocks dispatch removed: scatter computes its per-block prefix from
//    transposed histg[blk][bucket]; bucket bases via in-block scan of btot
//    (btot accumulated by count via global atomicAdd; memset to 0 first).
//  * aggs (depth-16, 2048 grid-stride), gemm2, fc: R14-identical.
//  * Dispatches: memset + 7 kernels (was 9 kernels).

constexpr int IN_DIM  = 128;
constexpr int HDIM    = 64;
constexpr int NBLK_A  = 256;   // count/scatter blocks
constexpr int BSH     = 8;     // bucket shift: 256 nodes per bucket
constexpr int MAXNB   = 512;   // max buckets supported (N <= 131072)
constexpr int HISTW   = 512;   // histg row width (buckets, padded)
constexpr int PADSLK  = 1792;  // per-bucket esrc slack: 256 nodes x 7 max pad

__device__ __forceinline__ float bf2f(unsigned int u) {
    return __uint_as_float(u << 16);
}
__device__ __forceinline__ unsigned short f2bf_bits(float f) {
    __hip_bfloat16 b = __float2bfloat16(f);
    return *(unsigned short*)&b;
}

// In-block inclusive scan of btot[0..NB) over MAXNB entries (256 threads,
// 2 elements/thread). bb[] ends inclusive; exclusive = bb[i] - btot[i].
__device__ __forceinline__ void bucket_scan(const int* __restrict__ btot,
                                            int* bb, int NB) {
    int tid = threadIdx.x;
    for (int i = tid; i < MAXNB; i += 256) bb[i] = (i < NB) ? btot[i] : 0;
    __syncthreads();
    for (int off = 1; off < MAXNB; off <<= 1) {
        int i0 = tid, i1 = tid + 256;
        int t0 = (i0 >= off) ? bb[i0 - off] : 0;
        int t1 = (i1 >= off) ? bb[i1 - off] : 0;
        __syncthreads();
        bb[i0] += t0;
        bb[i1] += t1;
        __syncthreads();
    }
}

// ---------- dense layers (R14 gemm_body) ----------

template<int K, bool IBF16, bool SCALE, bool BIAS, bool OBF16>
__device__ __forceinline__ void gemm_body(
        const void* __restrict__ Xv, const float* __restrict__ W,
        const float* __restrict__ bias, const float* __restrict__ dinv,
        void* __restrict__ Yv, int n, int bid) {
    constexpr int KC = 32;
    constexpr int XSTR = 132;                 // floats
    __shared__ float Xt[KC * XSTR];           // 16.9 KB
    __shared__ float Ws[KC * 64];             // 8 KB
    const int tid = threadIdx.x;
    const int node0 = bid * 128;
    const int r0 = (tid >> 4) * 8;            // 0..120
    const int c0 = (tid & 15) * 4;            // 0..60

    float acc[8][4];
#pragma unroll
    for (int a = 0; a < 8; ++a)
#pragma unroll
        for (int b = 0; b < 4; ++b) acc[a][b] = 0.f;

    for (int kc = 0; kc < K; kc += KC) {
        __syncthreads();
#pragma unroll
        for (int i = 0; i < 4; ++i) {
            int s = tid + i * 256;
            int row = s >> 3;
            int kq = s & 7;
            int grow = node0 + row;
            float4 v = make_float4(0.f, 0.f, 0.f, 0.f);
            if (grow < n) {
                if (IBF16) {
                    uint2 u = *(const uint2*)&((const unsigned short*)Xv)[(size_t)grow * K + kc + kq * 4];
                    v.x = bf2f(u.x & 0xffff); v.y = bf2f(u.x >> 16);
                    v.z = bf2f(u.y & 0xffff); v.w = bf2f(u.y >> 16);
                } else {
                    v = *(const float4*)&((const float*)Xv)[(size_t)grow * K + kc + kq * 4];
                }
            }
            Xt[(kq * 4 + 0) * XSTR + row] = v.x;
            Xt[(kq * 4 + 1) * XSTR + row] = v.y;
            Xt[(kq * 4 + 2) * XSTR + row] = v.z;
            Xt[(kq * 4 + 3) * XSTR + row] = v.w;
        }
#pragma unroll
        for (int i = 0; i < 2; ++i) {
            int s = tid + i * 256;
            *(float4*)&Ws[s * 4] = *(const float4*)&W[(size_t)kc * 64 + s * 4];
        }
        __syncthreads();
#pragma unroll
        for (int kk = 0; kk < KC; kk += 4) {
            float4 xa[4][2];
            float4 wv[4];
#pragma unroll
            for (int i = 0; i < 4; ++i) {
                xa[i][0] = *(const float4*)&Xt[(kk + i) * XSTR + r0];
                xa[i][1] = *(const float4*)&Xt[(kk + i) * XSTR + r0 + 4];
                wv[i]    = *(const float4*)&Ws[(kk + i) * 64 + c0];
            }
#pragma unroll
            for (int i = 0; i < 4; ++i) {
                const float* xp = (const float*)&xa[i][0];
                const float* wp = (const float*)&wv[i];
#pragma unroll
                for (int rr = 0; rr < 8; ++rr)
#pragma unroll
                    for (int cc = 0; cc < 4; ++cc)
                        acc[rr][cc] += xp[rr] * wp[cc];
            }
        }
    }
#pragma unroll
    for (int rr = 0; rr < 8; ++rr) {
        int node = node0 + r0 + rr;
        if (node < n) {
            float d = SCALE ? dinv[node] : 1.0f;
            float t[4];
#pragma unroll
            for (int cc = 0; cc < 4; ++cc) {
                float v = acc[rr][cc];
                if (BIAS) v += bias[c0 + cc];
                t[cc] = v * d;
            }
            if (OBF16) {
                __hip_bfloat16 vb[4];
#pragma unroll
                for (int cc = 0; cc < 4; ++cc) vb[cc] = __float2bfloat16(t[cc]);
                *(uint2*)&((__hip_bfloat16*)Yv)[(size_t)node * 64 + c0] = *(uint2*)vb;
            } else {
                *(float4*)&((float*)Yv)[(size_t)node * 64 + c0] = *(float4*)t;
            }
        }
    }
}

// ---------- D1: binA_count (blocks >= gB2) || gemm1 half A (blocks < gB2) ----------
// count: LDS histogram of dst buckets -> histg[cbid][bucket] (transposed
// layout, coalesced row write) + atomicAdd into btot (pre-zeroed).
__global__ __launch_bounds__(256, 4) void gemm1_count_kernel(
        const float* __restrict__ X, const float* __restrict__ W,
        unsigned short* __restrict__ Y,
        const int* __restrict__ dst, int* __restrict__ histg, int* __restrict__ btot,
        int gB2, int E, int NB, int chunk, int n) {
    if ((int)blockIdx.x >= gB2) {
        int cbid = (int)blockIdx.x - gB2;
        __shared__ int h[HISTW];
        for (int i = threadIdx.x; i < HISTW; i += 256) h[i] = 0;
        __syncthreads();
        int beg = cbid * chunk;
        int end = min(E, beg + chunk);
        for (int e = beg + threadIdx.x; e < end; e += 256)
            atomicAdd(&h[dst[e] >> BSH], 1);
        __syncthreads();
        for (int i = threadIdx.x; i < HISTW; i += 256) {
            int v = h[i];
            histg[cbid * HISTW + i] = v;
            if (v) atomicAdd(&btot[i], v);
        }
        return;
    }
    gemm_body<IN_DIM, false, false, false, true>(X, W, nullptr, nullptr, Y, n, blockIdx.x);
}

// ---------- D2: binA_scatter (blocks >= gB1b) || gemm1 half B ----------
// scatter block B: bucket bases from in-block scan of btot; per-block
// prefix by summing histg rows [0,B). Staging writes are bucket-cursor
// sequential (no write amplification).
__global__ __launch_bounds__(256, 4) void gemm1_scatter_kernel(
        const float* __restrict__ X, const float* __restrict__ W,
        unsigned short* __restrict__ Y,
        const int* __restrict__ src, const int* __restrict__ dst,
        const int* __restrict__ histg, const int* __restrict__ btot,
        int* __restrict__ staging, int gB1b, int gB2, int E, int NB, int chunk, int n) {
    if ((int)blockIdx.x >= gB1b) {
        int B = (int)blockIdx.x - gB1b;
        __shared__ int bb[MAXNB];
        __shared__ int cur[MAXNB];
        bucket_scan(btot, bb, NB);
        for (int t = threadIdx.x; t < HISTW; t += 256) {
            int s = bb[t] - btot[t];              // exclusive bucket base
            for (int r = 0; r < B; ++r) s += histg[r * HISTW + t];
            cur[t] = s;
        }
        __syncthreads();
        int beg = B * chunk;
        int end = min(E, beg + chunk);
        for (int e = beg + threadIdx.x; e < end; e += 256) {
            int s = src[e];
            int d = dst[e];
            int pos = atomicAdd(&cur[d >> BSH], 1);
            staging[pos] = (s << BSH) | (d & 255);  // src<2^17, local dst 8 bits
        }
        return;
    }
    gemm_body<IN_DIM, false, false, false, true>(X, W, nullptr, nullptr, Y, n,
                                                 gB2 + (int)blockIdx.x);
}

// ---------- D3: finalize: padded CSR + dinv + esrc + hp rescale ----------
__global__ void binB_finalize(const int* __restrict__ staging, const int* __restrict__ btot,
                              int2* __restrict__ rows, int* __restrict__ esrc,
                              float* __restrict__ dinv, uint4* __restrict__ hp4,
                              int N, int NB) {
    __shared__ int bb[MAXNB];
    __shared__ int cnt[256], sm[256], cur[256];
    __shared__ float dls[256];
    int tid = threadIdx.x;
    int b = blockIdx.x;
    bucket_scan(btot, bb, NB);
    int node0 = b << BSH;
    int nloc = min(256, N - node0);
    int eend = bb[b];
    int ebeg = eend - btot[b];
    int ebegP = ebeg + b * PADSLK;            // padded bucket base
    cnt[tid] = 0;
    dls[tid] = 1.0f;
    __syncthreads();
    for (int e = ebeg + tid; e < eend; e += 256)
        atomicAdd(&cnt[staging[e] & 255], 1);
    __syncthreads();
    int v = cnt[tid];
    int pv = (v + 7) & ~7;                    // padded count
    sm[tid] = pv;
    __syncthreads();
    for (int off = 1; off < 256; off <<= 1) {
        int t = (tid >= off) ? sm[tid - off] : 0;
        __syncthreads();
        sm[tid] += t;
        __syncthreads();
    }
    int excl = sm[tid] - pv;                  // padded exclusive offset
    cur[tid] = excl;
    __syncthreads();
    if (tid < nloc) {
        float d = rsqrtf((float)v + 1.0f);    // +1 self-loop
        rows[node0 + tid] = make_int2(ebegP + excl, ebegP + excl + pv);
        dinv[node0 + tid] = d;
        dls[tid] = d;
        for (int q = v; q < pv; ++q)          // fill pad slots -> zero row
            esrc[ebegP + excl + q] = N;
    }
    if (b == 0 && tid < 8) hp4[(size_t)N * 8 + tid] = make_uint4(0, 0, 0, 0);
    for (int e = ebeg + tid; e < eend; e += 256) {
        int p = staging[e];
        int pos = ebegP + atomicAdd(&cur[p & 255], 1);
        esrc[pos] = p >> BSH;
    }
    __syncthreads();
    // rescale hp rows of this bucket by dinv (gemm1 wrote unscaled bf16)
    int m = nloc * 8;                         // uint4 elements in this bucket
    uint4* hpq = hp4 + (size_t)node0 * 8;
    for (int q = tid; q < m; q += 256) {
        float dd = dls[q >> 3];
        uint4 u = hpq[q];
        unsigned int r[4];
        const unsigned int* up = &u.x;
#pragma unroll
        for (int c = 0; c < 4; ++c) {
            float lo = bf2f(up[c] & 0xffff) * dd;
            float hi = bf2f(up[c] >> 16) * dd;
            r[c] = (unsigned)f2bf_bits(lo) | ((unsigned)f2bf_bits(hi) << 16);
        }
        hpq[q] = make_uint4(r[0], r[1], r[2], r[3]);
    }
}

__global__ __launch_bounds__(256, 4) void gemm2_kernel(
        const void* X, const float* W, const float* dinv, void* Y, int n) {
    gemm_body<HDIM, true, true, false, true>(X, W, nullptr, dinv, Y, n, blockIdx.x);
}
__global__ __launch_bounds__(256, 4) void fc_kernel(
        const float* X, const float* W, const float* bias, void* Y, int n) {
    gemm_body<HDIM, false, false, true, false>(X, W, bias, nullptr, Y, n, blockIdx.x);
}

// ---------- aggregation: CSR-vector, 8 lanes per node (R14) ----------

template<bool OBF16>
__global__ __launch_bounds__(256) void agg_kernel(
        const uint4* __restrict__ hp4, const int* __restrict__ esrc,
        const int2* __restrict__ rows, const float* __restrict__ dinv,
        const float* __restrict__ bias, void* __restrict__ out, int n) {
    const int lane = threadIdx.x & 63;
    const int j = lane & 7;
    const int step = gridDim.x * 32;
    for (int idx = blockIdx.x * 32 + (threadIdx.x >> 6) * 8 + (lane >> 3);
         idx < n; idx += step) {
        const int node = idx;
        const int2 be = rows[node];

        float acc[8];
        {   // self-loop: own row
            uint4 u = hp4[(size_t)node * 8 + j];
            acc[0] = bf2f(u.x & 0xffff); acc[1] = bf2f(u.x >> 16);
            acc[2] = bf2f(u.y & 0xffff); acc[3] = bf2f(u.y >> 16);
            acc[4] = bf2f(u.z & 0xffff); acc[5] = bf2f(u.z >> 16);
            acc[6] = bf2f(u.w & 0xffff); acc[7] = bf2f(u.w >> 16);
        }
        int k = be.x;
        for (; k + 16 <= be.y; k += 16) {       // depth-16 batches
            int s[16];
#pragma unroll
            for (int i = 0; i < 16; ++i)
                s[i] = __builtin_nontemporal_load(&esrc[k + i]);
            uint4 u[16];
#pragma unroll
            for (int i = 0; i < 16; ++i)
                u[i] = hp4[(size_t)s[i] * 8 + j];
#pragma unroll
            for (int i = 0; i < 16; ++i) {
                acc[0] += bf2f(u[i].x & 0xffff); acc[1] += bf2f(u[i].x >> 16);
                acc[2] += bf2f(u[i].y & 0xffff); acc[3] += bf2f(u[i].y >> 16);
                acc[4] += bf2f(u[i].z & 0xffff); acc[5] += bf2f(u[i].z >> 16);
                acc[6] += bf2f(u[i].w & 0xffff); acc[7] += bf2f(u[i].w >> 16);
            }
        }
        if (k < be.y) {                          // padded => exactly 8 left
            int s[8];
#pragma unroll
            for (int i = 0; i < 8; ++i)
                s[i] = __builtin_nontemporal_load(&esrc[k + i]);
            uint4 u[8];
#pragma unroll
            for (int i = 0; i < 8; ++i)
                u[i] = hp4[(size_t)s[i] * 8 + j];
#pragma unroll
            for (int i = 0; i < 8; ++i) {
                acc[0] += bf2f(u[i].x & 0xffff); acc[1] += bf2f(u[i].x >> 16);
                acc[2] += bf2f(u[i].y & 0xffff); acc[3] += bf2f(u[i].y >> 16);
                acc[4] += bf2f(u[i].z & 0xffff); acc[5] += bf2f(u[i].z >> 16);
                acc[6] += bf2f(u[i].w & 0xffff); acc[7] += bf2f(u[i].w >> 16);
            }
        }
        const float d = dinv[node];
        float o[8];
#pragma unroll
        for (int t = 0; t < 8; ++t)
            o[t] = fmaxf(fmaf(d, acc[t], bias[8 * j + t]), 0.f);

        if (OBF16) {
            uint4 pk;
            pk.x = (unsigned)f2bf_bits(o[0]) | ((unsigned)f2bf_bits(o[1]) << 16);
            pk.y = (unsigned)f2bf_bits(o[2]) | ((unsigned)f2bf_bits(o[3]) << 16);
            pk.z = (unsigned)f2bf_bits(o[4]) | ((unsigned)f2bf_bits(o[5]) << 16);
            pk.w = (unsigned)f2bf_bits(o[6]) | ((unsigned)f2bf_bits(o[7]) << 16);
            ((uint4*)out)[(size_t)node * 8 + j] = pk;
        } else {
            ((float4*)out)[(size_t)node * 16 + 2 * j]     = make_float4(o[0], o[1], o[2], o[3]);
            ((float4*)out)[(size_t)node * 16 + 2 * j + 1] = make_float4(o[4], o[5], o[6], o[7]);
        }
    }
}

extern "C" void kernel_launch(void* const* d_in, const int* in_sizes, int n_in,
                              void* d_out, int out_size, void* d_ws, size_t ws_size,
                              hipStream_t stream) {
    const float* x   = (const float*)d_in[0];
    const float* W1  = (const float*)d_in[1];
    const float* b1  = (const float*)d_in[2];
    const float* W2  = (const float*)d_in[3];
    const float* b2  = (const float*)d_in[4];
    const float* Wfc = (const float*)d_in[5];
    const float* bfc = (const float*)d_in[6];
    const int*  eidx = (const int*)d_in[7];

    const int N = in_sizes[0] / IN_DIM;     // 100000
    const int E = in_sizes[7] / 2;          // 1600000
    const int* src = eidx;
    const int* dst = eidx + E;

    const int NB    = (N + 255) >> BSH;     // 391 buckets
    const int chunk = (E + NBLK_A - 1) / NBLK_A;
    const int EP    = E + NB * PADSLK;      // padded esrc capacity

    // ws layout (ints, 16B-aligned regions). staging is its OWN region now
    // (gemm1 writes hp concurrently with scatter writing staging):
    // rows[N] int2 | dinv[N] | histg[256*512] | btot[512] | staging[E]
    //   | esrc[EP] | hp[(N+1) rows x 128B] (row N zero) | h1[N rows x 128B]
    int* p = (int*)d_ws;
    int2* rows = (int2*)p;           p += (size_t)2 * N + 2;
    float* dinv = (float*)p;         p += (size_t)((N + 3) & ~3);
    int* histg = p;                  p += (size_t)NBLK_A * HISTW;
    int* btot = p;                   p += 512;
    int* staging = p;                p += (size_t)((E + 3) & ~3);
    int* esrc = p;                   p += (size_t)((EP + 3) & ~3);
    unsigned short* hp = (unsigned short*)p;   p += (size_t)(N + 1) * 32;
    unsigned short* h1 = (unsigned short*)p;   p += (size_t)N * 32;

    float* emb    = (float*)d_out;
    float* logits = emb + (size_t)N * HDIM;

    const int gB  = (N + 127) / 128;        // 782 gemm1 tiles
    const int gB2 = (gB + 1) / 2;           // half A tiles (391)
    const int gB1b = gB - gB2;              // half B tiles (391)
    const int aBlocks = 2048;               // 256 CU x 8 blocks, grid-stride

    // btot must start at zero (count accumulates atomically)
    hipMemsetAsync(btot, 0, 512 * sizeof(int), stream);

    // ---- D1: count || gemm1 half A (unscaled hp) ----
    gemm1_count_kernel<<<gB2 + NBLK_A, 256, 0, stream>>>(
        x, W1, hp, dst, histg, btot, gB2, E, NB, chunk, N);

    // ---- D2: scatter || gemm1 half B ----
    gemm1_scatter_kernel<<<gB1b + NBLK_A, 256, 0, stream>>>(
        x, W1, hp, src, dst, histg, btot, staging, gB1b, gB2, E, NB, chunk, N);

    // ---- D3: finalize (rows/dinv/esrc) + hp *= dinv rescale ----
    binB_finalize<<<NB, 256, 0, stream>>>(staging, btot, rows, esrc, dinv,
                                          (uint4*)hp, N, NB);

    // ---- layer 1 agg ----
    agg_kernel<true><<<aBlocks, 256, 0, stream>>>(
        (const uint4*)hp, esrc, rows, dinv, b1, h1, N);

    // ---- layer 2 ----
    gemm2_kernel<<<gB, 256, 0, stream>>>(h1, W2, dinv, hp, N);
    agg_kernel<false><<<aBlocks, 256, 0, stream>>>(
        (const uint4*)hp, esrc, rows, dinv, b2, emb, N);

    // ---- FC head ----
    fc_kernel<<<gB, 256, 0, stream>>>(emb, Wfc, bfc, logits, N);
}

// Round 11
// 286.867 us; speedup vs baseline: 1.4400x; 1.2206x over previous
//
#include <hip/hip_runtime.h>
#include <hip/hip_bf16.h>

// FlexibleGCN forward on MI355X — Round 19:
//  * Dense layers (gemm1, gemm2, fc) moved to MFMA (mfma_f32_16x16x32_bf16).
//    Block = 64 rows x 64 cols, 4 waves (each wave 16 rows); A staged in LDS
//    bf16 padded stride K+8 (2-way bank conflicts only); W transposed to
//    Wt[col][k] in LDS; output LDS-bounced for coalesced global writes.
//    C/D layout: col=lane&15, row=(lane>>4)*4+reg (HW-verified).
//    A/B frag: row/col=lane&15, k=(lane>>4)*8+j.
//  * CSR build + agg: byte-identical to R14 (best, 314.8us).

constexpr int IN_DIM  = 128;
constexpr int HDIM    = 64;
constexpr int NBLK_A  = 256;   // blocks in pass A (must match histg stride)
constexpr int BSH     = 8;     // bucket shift: 256 nodes per bucket
constexpr int MAXNB   = 512;   // max buckets supported (N <= 131072)
constexpr int PADSLK  = 1792;  // per-bucket esrc slack: 256 nodes x 7 max pad

typedef short bf16x8 __attribute__((ext_vector_type(8)));
typedef float f32x4  __attribute__((ext_vector_type(4)));

__device__ __forceinline__ float bf2f(unsigned int u) {
    return __uint_as_float(u << 16);
}
__device__ __forceinline__ unsigned short f2bf_bits(float f) {
    __hip_bfloat16 b = __float2bfloat16(f);
    return *(unsigned short*)&b;
}

// ---------- CSR build (R14) ----------

__global__ void binA_count(const int* __restrict__ dst, int* __restrict__ histg,
                           int E, int NB, int chunk) {
    __shared__ int h[MAXNB];
    for (int i = threadIdx.x; i < NB; i += 256) h[i] = 0;
    __syncthreads();
    int beg = blockIdx.x * chunk;
    int end = min(E, beg + chunk);
    for (int e = beg + threadIdx.x; e < end; e += 256)
        atomicAdd(&h[dst[e] >> BSH], 1);
    __syncthreads();
    for (int i = threadIdx.x; i < NB; i += 256)
        histg[i * NBLK_A + blockIdx.x] = h[i];
}

__global__ void binA_scanblocks(int* __restrict__ histg, int* __restrict__ btot) {
    __shared__ int sm[NBLK_A];
    int tid = threadIdx.x;
    int v = histg[blockIdx.x * NBLK_A + tid];
    sm[tid] = v;
    __syncthreads();
    for (int off = 1; off < NBLK_A; off <<= 1) {
        int t = (tid >= off) ? sm[tid - off] : 0;
        __syncthreads();
        sm[tid] += t;
        __syncthreads();
    }
    histg[blockIdx.x * NBLK_A + tid] = sm[tid] - v;   // exclusive
    if (tid == NBLK_A - 1) btot[blockIdx.x] = sm[tid];
}

// In-block inclusive scan of btot[0..NB) over MAXNB entries.
__device__ __forceinline__ void bucket_scan(const int* __restrict__ btot,
                                            int* bb, int NB) {
    int tid = threadIdx.x;
    for (int i = tid; i < MAXNB; i += 256) bb[i] = (i < NB) ? btot[i] : 0;
    __syncthreads();
    for (int off = 1; off < MAXNB; off <<= 1) {
        int i0 = tid, i1 = tid + 256;
        int t0 = (i0 >= off) ? bb[i0 - off] : 0;
        int t1 = (i1 >= off) ? bb[i1 - off] : 0;
        __syncthreads();
        bb[i0] += t0;
        bb[i1] += t1;
        __syncthreads();
    }
}

__global__ void binA_scatter(const int* __restrict__ src, const int* __restrict__ dst,
                             const int* __restrict__ histg, const int* __restrict__ btot,
                             int* __restrict__ staging, int E, int NB, int chunk) {
    __shared__ int bb[MAXNB];
    __shared__ int cur[MAXNB];
    bucket_scan(btot, bb, NB);
    for (int i = threadIdx.x; i < NB; i += 256)
        cur[i] = (bb[i] - btot[i]) + histg[i * NBLK_A + blockIdx.x];
    __syncthreads();
    int beg = blockIdx.x * chunk;
    int end = min(E, beg + chunk);
    for (int e = beg + threadIdx.x; e < end; e += 256) {
        int s = src[e];
        int d = dst[e];
        int pos = atomicAdd(&cur[d >> BSH], 1);
        staging[pos] = (s << BSH) | (d & 255);    // src<2^17, local dst 8 bits
    }
}

__global__ void binB_finalize(const int* __restrict__ staging, const int* __restrict__ btot,
                              int2* __restrict__ rows, int* __restrict__ esrc,
                              float* __restrict__ dinv, unsigned int* __restrict__ hp_rowN,
                              int N, int NB) {
    __shared__ int bb[MAXNB];
    __shared__ int cnt[256], sm[256], cur[256];
    int tid = threadIdx.x;
    int b = blockIdx.x;
    bucket_scan(btot, bb, NB);
    int node0 = b << BSH;
    int nloc = min(256, N - node0);
    int eend = bb[b];
    int ebeg = eend - btot[b];
    int ebegP = ebeg + b * PADSLK;            // padded bucket base
    cnt[tid] = 0;
    __syncthreads();
    for (int e = ebeg + tid; e < eend; e += 256)
        atomicAdd(&cnt[staging[e] & 255], 1);
    __syncthreads();
    int v = cnt[tid];
    int pv = (v + 7) & ~7;                    // padded count
    sm[tid] = pv;
    __syncthreads();
    for (int off = 1; off < 256; off <<= 1) {
        int t = (tid >= off) ? sm[tid - off] : 0;
        __syncthreads();
        sm[tid] += t;
        __syncthreads();
    }
    int excl = sm[tid] - pv;                  // padded exclusive offset
    cur[tid] = excl;
    __syncthreads();
    if (tid < nloc) {
        rows[node0 + tid] = make_int2(ebegP + excl, ebegP + excl + pv);
        dinv[node0 + tid] = rsqrtf((float)v + 1.0f);   // +1 self-loop
        for (int q = v; q < pv; ++q)          // fill pad slots -> zero row
            esrc[ebegP + excl + q] = N;
    }
    if (b == 0 && tid < 32) hp_rowN[tid] = 0u;         // zero hp row N (128B)
    for (int e = ebeg + tid; e < eend; e += 256) {
        int p = staging[e];
        int pos = ebegP + atomicAdd(&cur[p & 255], 1);
        esrc[pos] = p >> BSH;
    }
}

// ---------- dense layers: MFMA ----------
// Block: 256 thr = 4 waves; tile 64 rows x 64 cols; wave w owns rows
// w*16..w*16+15. K-loop in steps of 32 (mfma_f32_16x16x32_bf16).
// A staged as At[64][K+8] bf16; W transposed to Wt[64 cols][K+8] bf16.
// Frag mapping: A row / B col = lane&15, k = (lane>>4)*8 + j.
// D: col = lane&15, row = (lane>>4)*4 + reg.
template<int K, bool IBF16, bool SCALE, bool BIAS, bool OBF16>
__device__ __forceinline__ void mfma_gemm_body(
        const void* __restrict__ Xv, const float* __restrict__ W,
        const float* __restrict__ bias, const float* __restrict__ dinv,
        void* __restrict__ Yv, int n) {
    constexpr int STR = K + 8;                      // bf16 elems per row
    __shared__ short SMEM[2 * 64 * STR];            // At | Wt
    __shared__ float dls[64];
    short* At = SMEM;
    short* Wt = SMEM + 64 * STR;
    const int tid = threadIdx.x;
    const int node0 = blockIdx.x * 64;
    const int w = tid >> 6;
    const int lane = tid & 63;
    const int lrow = lane & 15;                     // A row / B col / D col
    const int khal = lane >> 4;                     // k-group 0..3

    // ---- stage A (bf16) ----
    if (IBF16) {                                    // bf16 input rows (K=64)
#pragma unroll
        for (int i = 0; i < K / 32; ++i) {
            int s = tid + i * 256;                  // 64*(K/8) uint4 chunks
            int row = s >> 3, j = s & 7;
            int grow = node0 + row;
            uint4 u = make_uint4(0, 0, 0, 0);
            if (grow < n)
                u = *(const uint4*)&((const unsigned short*)Xv)[(size_t)grow * K + j * 8];
            *(uint4*)&At[row * STR + j * 8] = u;
        }
    } else {                                        // fp32 input -> cvt
#pragma unroll
        for (int i = 0; i < K / 16; ++i) {
            int s = tid + i * 256;                  // 64*(K/4) float4 chunks
            int row = s / (K / 4), kq = s % (K / 4);
            int grow = node0 + row;
            float4 v = make_float4(0.f, 0.f, 0.f, 0.f);
            if (grow < n)
                v = *(const float4*)&((const float*)Xv)[(size_t)grow * K + kq * 4];
            unsigned short pk[4] = {f2bf_bits(v.x), f2bf_bits(v.y),
                                    f2bf_bits(v.z), f2bf_bits(v.w)};
            *(uint2*)&At[row * STR + kq * 4] = *(uint2*)pk;
        }
    }
    // ---- stage Wt (transposed, bf16) ----
#pragma unroll
    for (int i = 0; i < K / 4; ++i) {
        int s = tid + i * 256;                      // K*64 scalars
        int k = s >> 6, c = s & 63;
        Wt[c * STR + k] = (short)f2bf_bits(W[s]);
    }
    if (SCALE && tid < 64)
        dls[tid] = (node0 + tid < n) ? dinv[node0 + tid] : 1.0f;
    __syncthreads();

    // ---- MFMA ----
    f32x4 acc[4];
#pragma unroll
    for (int ct = 0; ct < 4; ++ct)
#pragma unroll
        for (int r = 0; r < 4; ++r) acc[ct][r] = 0.f;
#pragma unroll
    for (int kt = 0; kt < K / 32; ++kt) {
        int k0 = kt * 32 + khal * 8;
        bf16x8 a = *(bf16x8*)&At[(w * 16 + lrow) * STR + k0];
#pragma unroll
        for (int ct = 0; ct < 4; ++ct) {
            bf16x8 b = *(bf16x8*)&Wt[(ct * 16 + lrow) * STR + k0];
            acc[ct] = __builtin_amdgcn_mfma_f32_16x16x32_bf16(a, b, acc[ct], 0, 0, 0);
        }
    }
    __syncthreads();                                // At/Wt reads done

    // ---- epilogue -> LDS stage (aliases SMEM) ----
    short* Ot = SMEM;                               // [64][72] bf16
    float* Of = (float*)SMEM;                       // [64][68] f32
#pragma unroll
    for (int ct = 0; ct < 4; ++ct) {
#pragma unroll
        for (int r = 0; r < 4; ++r) {
            int row = w * 16 + khal * 4 + r;
            int col = ct * 16 + lrow;
            float v = acc[ct][r];
            if (BIAS) v += bias[col];
            if (SCALE) v *= dls[row];
            if (OBF16) Ot[row * 72 + col] = (short)f2bf_bits(v);
            else       Of[row * 68 + col] = v;
        }
    }
    __syncthreads();

    // ---- coalesced global write ----
    if (OBF16) {
#pragma unroll
        for (int i = 0; i < 2; ++i) {
            int s = tid + i * 256;                  // 512 uint4
            int row = s >> 3, j = s & 7;
            if (node0 + row < n)
                *(uint4*)&((unsigned short*)Yv)[(size_t)(node0 + row) * 64 + j * 8] =
                    *(uint4*)&Ot[row * 72 + j * 8];
        }
    } else {
#pragma unroll
        for (int i = 0; i < 4; ++i) {
            int s = tid + i * 256;                  // 1024 float4
            int row = s >> 4, q = s & 15;
            if (node0 + row < n)
                *(float4*)&((float*)Yv)[(size_t)(node0 + row) * 64 + q * 4] =
                    *(float4*)&Of[row * 68 + q * 4];
        }
    }
}

__global__ __launch_bounds__(256, 4) void mgemm1_kernel(
        const float* X, const float* W, const float* dinv, void* Y, int n) {
    mfma_gemm_body<IN_DIM, false, true, false, true>(X, W, nullptr, dinv, Y, n);
}
__global__ __launch_bounds__(256, 4) void mgemm2_kernel(
        const void* X, const float* W, const float* dinv, void* Y, int n) {
    mfma_gemm_body<HDIM, true, true, false, true>(X, W, nullptr, dinv, Y, n);
}
__global__ __launch_bounds__(256, 4) void mfc_kernel(
        const float* X, const float* W, const float* bias, void* Y, int n) {
    mfma_gemm_body<HDIM, false, false, true, false>(X, W, bias, nullptr, Y, n);
}

// ---------- aggregation: CSR-vector, 8 lanes per node (R14) ----------

template<bool OBF16>
__global__ __launch_bounds__(256) void agg_kernel(
        const uint4* __restrict__ hp4, const int* __restrict__ esrc,
        const int2* __restrict__ rows, const float* __restrict__ dinv,
        const float* __restrict__ bias, void* __restrict__ out, int n) {
    const int lane = threadIdx.x & 63;
    const int j = lane & 7;
    const int step = gridDim.x * 32;
    for (int idx = blockIdx.x * 32 + (threadIdx.x >> 6) * 8 + (lane >> 3);
         idx < n; idx += step) {
        const int node = idx;
        const int2 be = rows[node];

        float acc[8];
        {   // self-loop: own row
            uint4 u = hp4[(size_t)node * 8 + j];
            acc[0] = bf2f(u.x & 0xffff); acc[1] = bf2f(u.x >> 16);
            acc[2] = bf2f(u.y & 0xffff); acc[3] = bf2f(u.y >> 16);
            acc[4] = bf2f(u.z & 0xffff); acc[5] = bf2f(u.z >> 16);
            acc[6] = bf2f(u.w & 0xffff); acc[7] = bf2f(u.w >> 16);
        }
        int k = be.x;
        for (; k + 16 <= be.y; k += 16) {       // depth-16 batches
            int s[16];
#pragma unroll
            for (int i = 0; i < 16; ++i)
                s[i] = __builtin_nontemporal_load(&esrc[k + i]);
            uint4 u[16];
#pragma unroll
            for (int i = 0; i < 16; ++i)
                u[i] = hp4[(size_t)s[i] * 8 + j];
#pragma unroll
            for (int i = 0; i < 16; ++i) {
                acc[0] += bf2f(u[i].x & 0xffff); acc[1] += bf2f(u[i].x >> 16);
                acc[2] += bf2f(u[i].y & 0xffff); acc[3] += bf2f(u[i].y >> 16);
                acc[4] += bf2f(u[i].z & 0xffff); acc[5] += bf2f(u[i].z >> 16);
                acc[6] += bf2f(u[i].w & 0xffff); acc[7] += bf2f(u[i].w >> 16);
            }
        }
        if (k < be.y) {                          // padded => exactly 8 left
            int s[8];
#pragma unroll
            for (int i = 0; i < 8; ++i)
                s[i] = __builtin_nontemporal_load(&esrc[k + i]);
            uint4 u[8];
#pragma unroll
            for (int i = 0; i < 8; ++i)
                u[i] = hp4[(size_t)s[i] * 8 + j];
#pragma unroll
            for (int i = 0; i < 8; ++i) {
                acc[0] += bf2f(u[i].x & 0xffff); acc[1] += bf2f(u[i].x >> 16);
                acc[2] += bf2f(u[i].y & 0xffff); acc[3] += bf2f(u[i].y >> 16);
                acc[4] += bf2f(u[i].z & 0xffff); acc[5] += bf2f(u[i].z >> 16);
                acc[6] += bf2f(u[i].w & 0xffff); acc[7] += bf2f(u[i].w >> 16);
            }
        }
        const float d = dinv[node];
        float o[8];
#pragma unroll
        for (int t = 0; t < 8; ++t)
            o[t] = fmaxf(fmaf(d, acc[t], bias[8 * j + t]), 0.f);

        if (OBF16) {
            uint4 pk;
            pk.x = (unsigned)f2bf_bits(o[0]) | ((unsigned)f2bf_bits(o[1]) << 16);
            pk.y = (unsigned)f2bf_bits(o[2]) | ((unsigned)f2bf_bits(o[3]) << 16);
            pk.z = (unsigned)f2bf_bits(o[4]) | ((unsigned)f2bf_bits(o[5]) << 16);
            pk.w = (unsigned)f2bf_bits(o[6]) | ((unsigned)f2bf_bits(o[7]) << 16);
            ((uint4*)out)[(size_t)node * 8 + j] = pk;
        } else {
            ((float4*)out)[(size_t)node * 16 + 2 * j]     = make_float4(o[0], o[1], o[2], o[3]);
            ((float4*)out)[(size_t)node * 16 + 2 * j + 1] = make_float4(o[4], o[5], o[6], o[7]);
        }
    }
}

extern "C" void kernel_launch(void* const* d_in, const int* in_sizes, int n_in,
                              void* d_out, int out_size, void* d_ws, size_t ws_size,
                              hipStream_t stream) {
    const float* x   = (const float*)d_in[0];
    const float* W1  = (const float*)d_in[1];
    const float* b1  = (const float*)d_in[2];
    const float* W2  = (const float*)d_in[3];
    const float* b2  = (const float*)d_in[4];
    const float* Wfc = (const float*)d_in[5];
    const float* bfc = (const float*)d_in[6];
    const int*  eidx = (const int*)d_in[7];

    const int N = in_sizes[0] / IN_DIM;     // 100000
    const int E = in_sizes[7] / 2;          // 1600000
    const int* src = eidx;
    const int* dst = eidx + E;

    const int NB    = (N + 255) >> BSH;     // 391 buckets
    const int chunk = (E + NBLK_A - 1) / NBLK_A;
    const int EP    = E + NB * PADSLK;      // padded esrc capacity

    // ws layout (ints, regions 16B-aligned):
    // rows[N] int2 | dinv[N] | histg[NB*256] | btot[512]
    //   | esrc[EP] | hp[(N+1) rows x 128B] (row N zero) | h1[N rows x 128B]
    // staging int[E] aliases hp (dead before gemm1 writes hp).
    int* p = (int*)d_ws;
    int2* rows = (int2*)p;           p += (size_t)2 * N + 2;
    float* dinv = (float*)p;         p += (size_t)((N + 3) & ~3);
    int* histg = p;                  p += (size_t)((NB * NBLK_A + 3) & ~3);
    int* btot = p;                   p += 512;
    int* esrc = p;                   p += (size_t)((EP + 3) & ~3);
    unsigned short* hp = (unsigned short*)p;   p += (size_t)(N + 1) * 32;
    unsigned short* h1 = (unsigned short*)p;   p += (size_t)N * 32;
    int* staging = (int*)hp;                   // E ints < (N+1)*32 ints
    unsigned int* hp_rowN = (unsigned int*)(hp + (size_t)N * 64);

    float* emb    = (float*)d_out;
    float* logits = emb + (size_t)N * HDIM;

    // ---- CSR build (R14) ----
    binA_count<<<NBLK_A, 256, 0, stream>>>(dst, histg, E, NB, chunk);
    binA_scanblocks<<<NB, NBLK_A, 0, stream>>>(histg, btot);
    binA_scatter<<<NBLK_A, 256, 0, stream>>>(src, dst, histg, btot, staging, E, NB, chunk);
    binB_finalize<<<NB, 256, 0, stream>>>(staging, btot, rows, esrc, dinv, hp_rowN, N, NB);

    const int mB = (N + 63) / 64;           // 1563 MFMA tiles
    const int aBlocks = 2048;               // 256 CU x 8 blocks, grid-stride

    // ---- layer 1 ----
    mgemm1_kernel<<<mB, 256, 0, stream>>>(x, W1, dinv, hp, N);
    agg_kernel<true><<<aBlocks, 256, 0, stream>>>(
        (const uint4*)hp, esrc, rows, dinv, b1, h1, N);

    // ---- layer 2 ----
    mgemm2_kernel<<<mB, 256, 0, stream>>>(h1, W2, dinv, hp, N);
    agg_kernel<false><<<aBlocks, 256, 0, stream>>>(
        (const uint4*)hp, esrc, rows, dinv, b2, emb, N);

    // ---- FC head ----
    mfc_kernel<<<mB, 256, 0, stream>>>(emb, Wfc, bfc, logits, N);
}